// Round 1
// baseline (561.774 us; speedup 1.0000x reference)
//
#include <hip/hip_runtime.h>

typedef unsigned short u16;
using f32x4  = __attribute__((ext_vector_type(4))) float;
using bf16x8 = __attribute__((ext_vector_type(8))) short;

#define SEQ 4096
#define HS  1024
#define NHEAD 16
#define DH  64
#define NKB 64   // key blocks per sequence

__device__ __forceinline__ u16 f2bf(float f) {
  unsigned u = __float_as_uint(f);
  unsigned r = (u + 0x7fffu + ((u >> 16) & 1u)) >> 16;
  return (u16)r;
}

__device__ __forceinline__ void gl_lds16(const void* g, void* l) {
  __builtin_amdgcn_global_load_lds(
      (const __attribute__((address_space(1))) unsigned int*)g,
      (__attribute__((address_space(3))) unsigned int*)l, 16, 0, 0);
}

// ---------------- fp32 -> bf16 conversion ----------------
__global__ void cvt_kernel(const float* __restrict__ src, u16* __restrict__ dst, int n) {
  int idx = blockIdx.x * blockDim.x + threadIdx.x;
  int stride = gridDim.x * blockDim.x;
  for (int i = idx * 4; i < n; i += stride * 4) {
    float4 v = *reinterpret_cast<const float4*>(src + i);
    u16 o0 = f2bf(v.x), o1 = f2bf(v.y), o2 = f2bf(v.z), o3 = f2bf(v.w);
    unsigned lo = (unsigned)o0 | ((unsigned)o1 << 16);
    unsigned hi = (unsigned)o2 | ((unsigned)o3 << 16);
    uint2 pk; pk.x = lo; pk.y = hi;
    *reinterpret_cast<uint2*>(dst + i) = pk;
  }
}

// 3 weight matrices in one launch (blockIdx.y selects)
__global__ void cvt_w_kernel(const float* __restrict__ w0, const float* __restrict__ w1,
                             const float* __restrict__ w2,
                             u16* __restrict__ d0, u16* __restrict__ d1, u16* __restrict__ d2,
                             int n) {
  const float* s; u16* d;
  if (blockIdx.y == 0) { s = w0; d = d0; }
  else if (blockIdx.y == 1) { s = w1; d = d1; }
  else { s = w2; d = d2; }
  int idx = blockIdx.x * blockDim.x + threadIdx.x;
  int stride = gridDim.x * blockDim.x;
  for (int i = idx * 4; i < n; i += stride * 4) {
    float4 v = *reinterpret_cast<const float4*>(s + i);
    u16 o0 = f2bf(v.x), o1 = f2bf(v.y), o2 = f2bf(v.z), o3 = f2bf(v.w);
    unsigned lo = (unsigned)o0 | ((unsigned)o1 << 16);
    unsigned hi = (unsigned)o2 | ((unsigned)o3 << 16);
    uint2 pk; pk.x = lo; pk.y = hi;
    *reinterpret_cast<uint2*>(d + i) = pk;
  }
}

// ---------------- QKV projection GEMM (NT, bf16 in/out, fp32 acc) ----------------
// C[m,n] = sum_k X[m,k]*W[n,k] + bias[n]; M=16384, N=1024, K=1024
// 128x128 tile, BK=64, 4 waves (2x2), each wave 64x64 via 4x4 16x16x32 MFMA frags.
__global__ void gemm_qkv(const u16* __restrict__ X,
                         const u16* __restrict__ Wq, const u16* __restrict__ Wk,
                         const u16* __restrict__ Wv,
                         const float* __restrict__ bq, const float* __restrict__ bk,
                         const float* __restrict__ bv,
                         u16* __restrict__ Q, u16* __restrict__ K, u16* __restrict__ V) {
  const u16* W; const float* bias; u16* O;
  if (blockIdx.z == 0)      { W = Wq; bias = bq; O = Q; }
  else if (blockIdx.z == 1) { W = Wk; bias = bk; O = K; }
  else                      { W = Wv; bias = bv; O = V; }

  __shared__ u16 As[128 * 64];
  __shared__ u16 Bs[128 * 64];

  const int tid = threadIdx.x;
  const int lane = tid & 63;
  const int w = tid >> 6;
  const int wr = w >> 1, wc = w & 1;
  const int m0 = blockIdx.x * 128;
  const int n0 = blockIdx.y * 128;

  f32x4 acc[4][4] = {};

  const int srow = lane >> 3;         // 0..7
  const int scol = (lane & 7) * 8;    // element col

  for (int k0 = 0; k0 < HS; k0 += 64) {
#pragma unroll
    for (int t = 0; t < 4; ++t) {
      int sub = w * 4 + t;
      int r = sub * 8 + srow;
      gl_lds16(X + (size_t)(m0 + r) * HS + k0 + scol, As + sub * 512);
      gl_lds16(W + (size_t)(n0 + r) * HS + k0 + scol, Bs + sub * 512);
    }
    __syncthreads();
#pragma unroll
    for (int ks = 0; ks < 2; ++ks) {
      bf16x8 a[4], b[4];
#pragma unroll
      for (int mf = 0; mf < 4; ++mf)
        a[mf] = *reinterpret_cast<const bf16x8*>(
            As + (wr * 64 + mf * 16 + (lane & 15)) * 64 + ks * 32 + (lane >> 4) * 8);
#pragma unroll
      for (int nf = 0; nf < 4; ++nf)
        b[nf] = *reinterpret_cast<const bf16x8*>(
            Bs + (wc * 64 + nf * 16 + (lane & 15)) * 64 + ks * 32 + (lane >> 4) * 8);
#pragma unroll
      for (int mf = 0; mf < 4; ++mf)
#pragma unroll
        for (int nf = 0; nf < 4; ++nf)
          acc[mf][nf] = __builtin_amdgcn_mfma_f32_16x16x32_bf16(a[mf], b[nf], acc[mf][nf], 0, 0, 0);
    }
    __syncthreads();
  }

#pragma unroll
  for (int nf = 0; nf < 4; ++nf) {
    int c = n0 + wc * 64 + nf * 16 + (lane & 15);
    float bval = bias[c];
#pragma unroll
    for (int mf = 0; mf < 4; ++mf) {
#pragma unroll
      for (int j = 0; j < 4; ++j) {
        int r = m0 + wr * 64 + mf * 16 + (lane >> 4) * 4 + j;
        O[(size_t)r * HS + c] = f2bf(acc[mf][nf][j] + bval);
      }
    }
  }
}

// ---------------- BigBird block-sparse attention ----------------
// One workgroup per (q-block, head, batch). 4 waves x 16 q-rows.
// Swapped QK^T (mfma(K,Q)) -> per-lane holds full 64-score row slice for one q-row.
__global__ void bigbird_attn(const u16* __restrict__ Q, const u16* __restrict__ K,
                             const u16* __restrict__ V, float* __restrict__ OUT) {
  const int qb = blockIdx.x;  // 0..63
  const int h  = blockIdx.y;  // 0..15
  const int b  = blockIdx.z;  // 0..3

  __shared__ u16 Qs[64 * 64];
  __shared__ u16 Ks[64 * 64];
  __shared__ u16 Vt[64 * 72];  // V transposed [d][k], padded stride 72
  __shared__ u16 Ps[64 * 72];  // P [q-row][k], padded stride 72

  const int tid = threadIdx.x;
  const int lane = tid & 63;
  const int w = tid >> 6;
  const int g = lane >> 4;
  const int c = lane & 15;

  const size_t base_bh = (size_t)b * SEQ * HS + (size_t)h * DH;

  // stage Q (XOR-swizzled columns; source pre-swizzle since global_load_lds is linear)
  {
    const u16* qg = Q + base_bh + (size_t)qb * 64 * HS;
#pragma unroll
    for (int t = 0; t < 2; ++t) {
      int sub = w * 2 + t;
      int r = sub * 8 + (lane >> 3);
      int c16 = (lane & 7) ^ (r & 7);
      gl_lds16(qg + (size_t)r * HS + c16 * 8, Qs + sub * 512);
    }
  }

  int nkb;
  if (qb == 0 || qb == 63) nkb = 64;
  else if (qb == 1 || qb == 62) nkb = 4;
  else nkb = 5;

  float m_run = -1e30f;
  float l_run = 0.f;
  f32x4 o_acc[4] = {};

  const float scale = 0.125f;  // 1/sqrt(64)

  for (int it = 0; it < nkb; ++it) {
    int kb;
    if (qb == 0 || qb == 63) kb = it;
    else if (qb == 1)  kb = (it == 3) ? 63 : it;
    else if (qb == 62) kb = (it == 0) ? 0 : (60 + it);
    else               kb = (it == 0) ? 0 : ((it == 4) ? 63 : (qb - 2 + it));

    const u16* kg = K + base_bh + (size_t)kb * 64 * HS;
    const u16* vg = V + base_bh + (size_t)kb * 64 * HS;

    // stage K (swizzled, via global_load_lds)
#pragma unroll
    for (int t = 0; t < 2; ++t) {
      int sub = w * 2 + t;
      int r = sub * 8 + (lane >> 3);
      int c16 = (lane & 7) ^ (r & 7);
      gl_lds16(kg + (size_t)r * HS + c16 * 8, Ks + sub * 512);
    }
    // stage V transposed (reg path: coalesced global read, scatter LDS write)
    {
      int krow = tid >> 2;
      int dseg = (tid & 3) * 16;
      bf16x8 v0 = *reinterpret_cast<const bf16x8*>(vg + (size_t)krow * HS + dseg);
      bf16x8 v1 = *reinterpret_cast<const bf16x8*>(vg + (size_t)krow * HS + dseg + 8);
#pragma unroll
      for (int j = 0; j < 8; ++j) {
        Vt[(dseg + j) * 72 + krow]     = (u16)v0[j];
        Vt[(dseg + 8 + j) * 72 + krow] = (u16)v1[j];
      }
    }
    __syncthreads();

    // S^T = K * Q^T : acc_s[mf] holds S^T[k=mf*16+g*4+j][q-local=c]
    f32x4 accs[4] = {};
#pragma unroll
    for (int ks = 0; ks < 2; ++ks) {
      bf16x8 qf, kf[4];
      {
        int r = w * 16 + c;
        int c16 = (ks * 4 + g) ^ (r & 7);
        qf = *reinterpret_cast<const bf16x8*>(Qs + r * 64 + c16 * 8);
      }
#pragma unroll
      for (int mf = 0; mf < 4; ++mf) {
        int r = mf * 16 + c;
        int c16 = (ks * 4 + g) ^ (r & 7);
        kf[mf] = *reinterpret_cast<const bf16x8*>(Ks + r * 64 + c16 * 8);
      }
#pragma unroll
      for (int mf = 0; mf < 4; ++mf)
        accs[mf] = __builtin_amdgcn_mfma_f32_16x16x32_bf16(kf[mf], qf, accs[mf], 0, 0, 0);
    }

    // online softmax, per-lane q-row = w*16 + c; scores in sv[0..15]
    float sv[16];
    float smax = -1e30f;
#pragma unroll
    for (int mf = 0; mf < 4; ++mf)
#pragma unroll
      for (int j = 0; j < 4; ++j) {
        float s = accs[mf][j] * scale;
        sv[mf * 4 + j] = s;
        smax = fmaxf(smax, s);
      }
    smax = fmaxf(smax, __shfl_xor(smax, 16));
    smax = fmaxf(smax, __shfl_xor(smax, 32));
    float m_new = fmaxf(m_run, smax);
    float corr = __expf(m_run - m_new);
    float psum = 0.f;
    u16 pb[16];
#pragma unroll
    for (int i = 0; i < 16; ++i) {
      float p = __expf(sv[i] - m_new);
      psum += p;
      pb[i] = f2bf(p);
    }
    psum += __shfl_xor(psum, 16);
    psum += __shfl_xor(psum, 32);
    l_run = l_run * corr + psum;
    m_run = m_new;

    // rescale O: O rows are w*16 + g*4 + j -> fetch corr from lane (g*4+j)
#pragma unroll
    for (int j = 0; j < 4; ++j) {
      float cj = __shfl(corr, g * 4 + j);
#pragma unroll
      for (int df = 0; df < 4; ++df) o_acc[df][j] *= cj;
    }

    // write P[q-row][k] as bf16 (b64 packed writes)
    {
      int r = w * 16 + c;
#pragma unroll
      for (int mf = 0; mf < 4; ++mf) {
        unsigned lo = (unsigned)pb[mf * 4 + 0] | ((unsigned)pb[mf * 4 + 1] << 16);
        unsigned hi = (unsigned)pb[mf * 4 + 2] | ((unsigned)pb[mf * 4 + 3] << 16);
        uint2 pk; pk.x = lo; pk.y = hi;
        *reinterpret_cast<uint2*>(Ps + r * 72 + mf * 16 + g * 4) = pk;
      }
    }

    // PV: O[r][d] += P[r][k] * V[k][d]
#pragma unroll
    for (int ks = 0; ks < 2; ++ks) {
      bf16x8 pf = *reinterpret_cast<const bf16x8*>(
          Ps + (w * 16 + c) * 72 + ks * 32 + g * 8);
#pragma unroll
      for (int df = 0; df < 4; ++df) {
        bf16x8 vf = *reinterpret_cast<const bf16x8*>(
            Vt + (df * 16 + c) * 72 + ks * 32 + g * 8);
        o_acc[df] = __builtin_amdgcn_mfma_f32_16x16x32_bf16(pf, vf, o_acc[df], 0, 0, 0);
      }
    }
    __syncthreads();
  }

  // epilogue: divide by l, store fp32
#pragma unroll
  for (int j = 0; j < 4; ++j) {
    float lr = __shfl(l_run, g * 4 + j);
    float inv = 1.f / lr;
    int r = qb * 64 + w * 16 + g * 4 + j;
    size_t rowbase = ((size_t)b * SEQ + r) * HS + (size_t)h * DH;
#pragma unroll
    for (int df = 0; df < 4; ++df)
      OUT[rowbase + df * 16 + c] = o_acc[df][j] * inv;
  }
}

extern "C" void kernel_launch(void* const* d_in, const int* in_sizes, int n_in,
                              void* d_out, int out_size, void* d_ws, size_t ws_size,
                              hipStream_t stream) {
  const float* X  = (const float*)d_in[0];
  const float* Wq = (const float*)d_in[1];
  const float* bq = (const float*)d_in[2];
  const float* Wk = (const float*)d_in[3];
  const float* bk = (const float*)d_in[4];
  const float* Wv = (const float*)d_in[5];
  const float* bv = (const float*)d_in[6];
  float* out = (float*)d_out;

  u16* Xb  = (u16*)d_ws;                 // 16,777,216 elems
  u16* Wqb = Xb + 16777216;              // 1,048,576
  u16* Wkb = Wqb + 1048576;
  u16* Wvb = Wkb + 1048576;
  u16* Qb  = Wvb + 1048576;              // 16,777,216 each
  u16* Kb  = Qb + 16777216;
  u16* Vb  = Kb + 16777216;

  cvt_kernel<<<2048, 256, 0, stream>>>(X, Xb, 16777216);
  cvt_w_kernel<<<dim3(256, 3), 256, 0, stream>>>(Wq, Wk, Wv, Wqb, Wkb, Wvb, 1048576);
  gemm_qkv<<<dim3(128, 8, 3), 256, 0, stream>>>(Xb, Wqb, Wkb, Wvb, bq, bk, bv, Qb, Kb, Vb);
  bigbird_attn<<<dim3(64, NHEAD, 4), 256, 0, stream>>>(Qb, Kb, Vb, out);
}

// Round 2
// 254.824 us; speedup vs baseline: 2.2046x; 2.2046x over previous
//
#include <hip/hip_runtime.h>

typedef unsigned short u16;
using f32x4  = __attribute__((ext_vector_type(4))) float;
using bf16x8 = __attribute__((ext_vector_type(8))) short;

#define SEQ 4096
#define HS  1024
#define NHEAD 16
#define DH  64

__device__ __forceinline__ u16 f2bf(float f) {
  unsigned u = __float_as_uint(f);
  unsigned r = (u + 0x7fffu + ((u >> 16) & 1u)) >> 16;
  return (u16)r;
}

__device__ __forceinline__ void gl_lds16(const void* g, void* l) {
  __builtin_amdgcn_global_load_lds(
      (const __attribute__((address_space(1))) unsigned int*)g,
      (__attribute__((address_space(3))) unsigned int*)l, 16, 0, 0);
}

// ---------------- fp32 -> bf16 conversion ----------------
__global__ void cvt_kernel(const float* __restrict__ src, u16* __restrict__ dst, int n) {
  int idx = blockIdx.x * blockDim.x + threadIdx.x;
  int stride = gridDim.x * blockDim.x;
  for (int i = idx * 4; i < n; i += stride * 4) {
    float4 v = *reinterpret_cast<const float4*>(src + i);
    u16 o0 = f2bf(v.x), o1 = f2bf(v.y), o2 = f2bf(v.z), o3 = f2bf(v.w);
    unsigned lo = (unsigned)o0 | ((unsigned)o1 << 16);
    unsigned hi = (unsigned)o2 | ((unsigned)o3 << 16);
    uint2 pk; pk.x = lo; pk.y = hi;
    *reinterpret_cast<uint2*>(dst + i) = pk;
  }
}

__global__ void cvt_w_kernel(const float* __restrict__ w0, const float* __restrict__ w1,
                             const float* __restrict__ w2,
                             u16* __restrict__ d0, u16* __restrict__ d1, u16* __restrict__ d2,
                             int n) {
  const float* s; u16* d;
  if (blockIdx.y == 0) { s = w0; d = d0; }
  else if (blockIdx.y == 1) { s = w1; d = d1; }
  else { s = w2; d = d2; }
  int idx = blockIdx.x * blockDim.x + threadIdx.x;
  int stride = gridDim.x * blockDim.x;
  for (int i = idx * 4; i < n; i += stride * 4) {
    float4 v = *reinterpret_cast<const float4*>(s + i);
    u16 o0 = f2bf(v.x), o1 = f2bf(v.y), o2 = f2bf(v.z), o3 = f2bf(v.w);
    unsigned lo = (unsigned)o0 | ((unsigned)o1 << 16);
    unsigned hi = (unsigned)o2 | ((unsigned)o3 << 16);
    uint2 pk; pk.x = lo; pk.y = hi;
    *reinterpret_cast<uint2*>(d + i) = pk;
  }
}

// ---------------- QKV projection GEMM (NT, bf16 in/out, fp32 acc) ----------------
__global__ void gemm_qkv(const u16* __restrict__ X,
                         const u16* __restrict__ Wq, const u16* __restrict__ Wk,
                         const u16* __restrict__ Wv,
                         const float* __restrict__ bq, const float* __restrict__ bk,
                         const float* __restrict__ bv,
                         u16* __restrict__ Q, u16* __restrict__ K, u16* __restrict__ V) {
  const u16* W; const float* bias; u16* O;
  if (blockIdx.z == 0)      { W = Wq; bias = bq; O = Q; }
  else if (blockIdx.z == 1) { W = Wk; bias = bk; O = K; }
  else                      { W = Wv; bias = bv; O = V; }

  __shared__ u16 As[128 * 64];
  __shared__ u16 Bs[128 * 64];

  const int tid = threadIdx.x;
  const int lane = tid & 63;
  const int w = tid >> 6;
  const int wr = w >> 1, wc = w & 1;
  const int m0 = blockIdx.x * 128;
  const int n0 = blockIdx.y * 128;

  f32x4 acc[4][4] = {};

  const int srow = lane >> 3;
  const int scol = (lane & 7) * 8;

  for (int k0 = 0; k0 < HS; k0 += 64) {
#pragma unroll
    for (int t = 0; t < 4; ++t) {
      int sub = w * 4 + t;
      int r = sub * 8 + srow;
      gl_lds16(X + (size_t)(m0 + r) * HS + k0 + scol, As + sub * 512);
      gl_lds16(W + (size_t)(n0 + r) * HS + k0 + scol, Bs + sub * 512);
    }
    __syncthreads();
#pragma unroll
    for (int ks = 0; ks < 2; ++ks) {
      bf16x8 a[4], b[4];
#pragma unroll
      for (int mf = 0; mf < 4; ++mf)
        a[mf] = *reinterpret_cast<const bf16x8*>(
            As + (wr * 64 + mf * 16 + (lane & 15)) * 64 + ks * 32 + (lane >> 4) * 8);
#pragma unroll
      for (int nf = 0; nf < 4; ++nf)
        b[nf] = *reinterpret_cast<const bf16x8*>(
            Bs + (wc * 64 + nf * 16 + (lane & 15)) * 64 + ks * 32 + (lane >> 4) * 8);
#pragma unroll
      for (int mf = 0; mf < 4; ++mf)
#pragma unroll
        for (int nf = 0; nf < 4; ++nf)
          acc[mf][nf] = __builtin_amdgcn_mfma_f32_16x16x32_bf16(a[mf], b[nf], acc[mf][nf], 0, 0, 0);
    }
    __syncthreads();
  }

#pragma unroll
  for (int nf = 0; nf < 4; ++nf) {
    int cc = n0 + wc * 64 + nf * 16 + (lane & 15);
    float bval = bias[cc];
#pragma unroll
    for (int mf = 0; mf < 4; ++mf) {
#pragma unroll
      for (int j = 0; j < 4; ++j) {
        int r = m0 + wr * 64 + mf * 16 + (lane >> 4) * 4 + j;
        O[(size_t)r * HS + cc] = f2bf(acc[mf][nf][j] + bval);
      }
    }
  }
}

// ---------------- BigBird block-sparse attention (load-balanced) ----------------
// Grid: 3968 main wgs (qb 1..62; 4-5 k-blocks each, direct output) +
//       2048 heavy wgs (qb 0/63 split into 16 segments x 4 k-blocks; partial out).
__global__ void bigbird_attn2(const u16* __restrict__ Q, const u16* __restrict__ K,
                              const u16* __restrict__ V, float* __restrict__ OUT,
                              float* __restrict__ Opart, float* __restrict__ MLpart) {
  __shared__ u16 Qs[64 * 64];
  __shared__ u16 Ks[2][64 * 64];
  __shared__ u16 Vt[64 * 72];
  __shared__ u16 Ps[64 * 72];

  const int tid = threadIdx.x;
  const int lane = tid & 63;
  const int w = tid >> 6;
  const int g = lane >> 4;
  const int c = lane & 15;

  int bid = blockIdx.x;
  int qb, b, h, nkb, seg4 = 0, p = 0;
  bool heavy;
  if (bid < 3968) {
    heavy = false;
    b = bid & 3; int t = bid >> 2; h = t & 15; qb = (t >> 4) + 1;
    nkb = (qb == 1 || qb == 62) ? 4 : 5;
  } else {
    heavy = true;
    int t = bid - 3968;
    b = t & 3; t >>= 2; h = t & 15; t >>= 4;   // 0..31
    int seg = t & 15; int q2 = t >> 4;
    qb = q2 ? 63 : 0; seg4 = seg * 4; nkb = 4;
    p = ((q2 * 16 + h) * 4 + b) * 16 + seg;
  }

  const size_t base_bh = (size_t)b * SEQ * HS + (size_t)h * DH;

  auto kb_of = [&](int it) -> int {
    if (heavy) return seg4 + it;
    if (qb == 1)  return (it == 3) ? 63 : it;
    if (qb == 62) return (it == 0) ? 0 : 60 + it;
    return (it == 0) ? 0 : ((it == 4) ? 63 : qb - 2 + it);
  };

  // stage Q (chunk-XOR swizzle via pre-swizzled source)
  {
    const u16* qg = Q + base_bh + (size_t)qb * 64 * HS;
#pragma unroll
    for (int t2 = 0; t2 < 2; ++t2) {
      int sub = w * 2 + t2;
      int r = sub * 8 + (lane >> 3);
      int c16 = (lane & 7) ^ (r & 7);
      gl_lds16(qg + (size_t)r * HS + c16 * 8, Qs + sub * 512);
    }
  }
  // stage K(0), prefetch V(0) into regs
  int kb0 = kb_of(0);
  {
    const u16* kg = K + base_bh + (size_t)kb0 * 64 * HS;
#pragma unroll
    for (int t2 = 0; t2 < 2; ++t2) {
      int sub = w * 2 + t2;
      int r = sub * 8 + (lane >> 3);
      int c16 = (lane & 7) ^ (r & 7);
      gl_lds16(kg + (size_t)r * HS + c16 * 8, Ks[0] + sub * 512);
    }
  }
  bf16x8 vr0, vr1;
  {
    const u16* vg = V + base_bh + (size_t)kb0 * 64 * HS;
    int krow = tid >> 2, dseg = (tid & 3) * 16;
    vr0 = *reinterpret_cast<const bf16x8*>(vg + (size_t)krow * HS + dseg);
    vr1 = *reinterpret_cast<const bf16x8*>(vg + (size_t)krow * HS + dseg + 8);
  }
  __syncthreads();

  // hoist Q fragments
  bf16x8 qf[2];
#pragma unroll
  for (int ks = 0; ks < 2; ++ks) {
    int r = w * 16 + c;
    int c16 = (ks * 4 + g) ^ (r & 7);
    qf[ks] = *reinterpret_cast<const bf16x8*>(Qs + r * 64 + c16 * 8);
  }

  float m_run = -1e30f, l_run = 0.f;
  f32x4 o_acc[4] = {};
  const float scale = 0.125f;

  for (int it = 0; it < nkb; ++it) {
    const int cur = it & 1;
    // scatter V into Vt (transposed [d][k], stride 72)
    {
      int krow = tid >> 2, dseg = (tid & 3) * 16;
#pragma unroll
      for (int j2 = 0; j2 < 8; ++j2) {
        Vt[(dseg + j2) * 72 + krow]     = (u16)vr0[j2];
        Vt[(dseg + 8 + j2) * 72 + krow] = (u16)vr1[j2];
      }
    }
    // prefetch next K (gl_lds) + next V (regs) — latency hides under QK+softmax
    if (it + 1 < nkb) {
      int kbn = kb_of(it + 1);
      const u16* kg = K + base_bh + (size_t)kbn * 64 * HS;
#pragma unroll
      for (int t2 = 0; t2 < 2; ++t2) {
        int sub = w * 2 + t2;
        int r = sub * 8 + (lane >> 3);
        int c16 = (lane & 7) ^ (r & 7);
        gl_lds16(kg + (size_t)r * HS + c16 * 8, Ks[cur ^ 1] + sub * 512);
      }
      const u16* vg = V + base_bh + (size_t)kbn * 64 * HS;
      int krow = tid >> 2, dseg = (tid & 3) * 16;
      vr0 = *reinterpret_cast<const bf16x8*>(vg + (size_t)krow * HS + dseg);
      vr1 = *reinterpret_cast<const bf16x8*>(vg + (size_t)krow * HS + dseg + 8);
    }

    // S^T = K * Q^T
    f32x4 accs[4] = {};
#pragma unroll
    for (int ks = 0; ks < 2; ++ks) {
#pragma unroll
      for (int mf = 0; mf < 4; ++mf) {
        int r = mf * 16 + c;
        int c16 = (ks * 4 + g) ^ (r & 7);
        bf16x8 kf = *reinterpret_cast<const bf16x8*>(Ks[cur] + r * 64 + c16 * 8);
        accs[mf] = __builtin_amdgcn_mfma_f32_16x16x32_bf16(kf, qf[ks], accs[mf], 0, 0, 0);
      }
    }

    // online softmax: per-lane q-row = w*16 + c
    float sv[16];
    float smax = -1e30f;
#pragma unroll
    for (int mf = 0; mf < 4; ++mf)
#pragma unroll
      for (int j = 0; j < 4; ++j) {
        float s = accs[mf][j] * scale;
        sv[mf * 4 + j] = s;
        smax = fmaxf(smax, s);
      }
    smax = fmaxf(smax, __shfl_xor(smax, 16));
    smax = fmaxf(smax, __shfl_xor(smax, 32));
    float m_new = fmaxf(m_run, smax);
    float corr = __expf(m_run - m_new);
    float psum = 0.f;
    u16 pb[16];
#pragma unroll
    for (int i = 0; i < 16; ++i) {
      float pv = __expf(sv[i] - m_new);
      psum += pv;
      pb[i] = f2bf(pv);
    }
    psum += __shfl_xor(psum, 16);
    psum += __shfl_xor(psum, 32);
    l_run = l_run * corr + psum;
    m_run = m_new;

    // rescale O
#pragma unroll
    for (int j = 0; j < 4; ++j) {
      float cj = __shfl(corr, g * 4 + j);
#pragma unroll
      for (int df = 0; df < 4; ++df) o_acc[df][j] *= cj;
    }

    // write P
    {
      int r = w * 16 + c;
#pragma unroll
      for (int mf = 0; mf < 4; ++mf) {
        unsigned lo = (unsigned)pb[mf * 4 + 0] | ((unsigned)pb[mf * 4 + 1] << 16);
        unsigned hi = (unsigned)pb[mf * 4 + 2] | ((unsigned)pb[mf * 4 + 3] << 16);
        uint2 pk; pk.x = lo; pk.y = hi;
        *reinterpret_cast<uint2*>(Ps + r * 72 + mf * 16 + g * 4) = pk;
      }
    }

    __syncthreads();  // B1: Vt + Ps visible

    // PV
#pragma unroll
    for (int ks = 0; ks < 2; ++ks) {
      bf16x8 pf = *reinterpret_cast<const bf16x8*>(Ps + (w * 16 + c) * 72 + ks * 32 + g * 8);
#pragma unroll
      for (int df = 0; df < 4; ++df) {
        bf16x8 vf = *reinterpret_cast<const bf16x8*>(Vt + (df * 16 + c) * 72 + ks * 32 + g * 8);
        o_acc[df] = __builtin_amdgcn_mfma_f32_16x16x32_bf16(pf, vf, o_acc[df], 0, 0, 0);
      }
    }

    __syncthreads();  // B2: PV done before next iter's Vt/Ps writes
  }

  if (!heavy) {
#pragma unroll
    for (int j = 0; j < 4; ++j) {
      float lr = __shfl(l_run, g * 4 + j);
      float inv = 1.f / lr;
      int r = qb * 64 + w * 16 + g * 4 + j;
      size_t rowbase = ((size_t)b * SEQ + r) * HS + (size_t)h * DH;
#pragma unroll
      for (int df = 0; df < 4; ++df)
        OUT[rowbase + df * 16 + c] = o_acc[df][j] * inv;
    }
  } else {
    // unnormalized partials
#pragma unroll
    for (int j = 0; j < 4; ++j) {
      int row = w * 16 + g * 4 + j;
#pragma unroll
      for (int df = 0; df < 4; ++df)
        Opart[(size_t)p * 4096 + row * 64 + df * 16 + c] = o_acc[df][j];
    }
    if (g == 0) {
      int row = w * 16 + c;
      MLpart[(size_t)p * 128 + row * 2]     = m_run;
      MLpart[(size_t)p * 128 + row * 2 + 1] = l_run;
    }
  }
}

// ---------------- combine partials for qb 0 / 63 ----------------
__global__ void bigbird_combine(const float* __restrict__ Opart, const float* __restrict__ MLpart,
                                float* __restrict__ OUT) {
  int bid = blockIdx.x;               // 128 = (q2, h, b)
  int b = bid & 3; int t = bid >> 2; int h = t & 15; int q2 = t >> 4;
  int qb = q2 ? 63 : 0;
  int w = threadIdx.x >> 6, lane = threadIdx.x & 63;
  int pbase = ((q2 * 16 + h) * 4 + b) * 16;
#pragma unroll 1
  for (int rr = 0; rr < 16; ++rr) {
    int row = w * 16 + rr;
    float ms[16], ls[16];
    float M = -1e30f;
#pragma unroll
    for (int s = 0; s < 16; ++s) {
      ms[s] = MLpart[(size_t)(pbase + s) * 128 + row * 2];
      ls[s] = MLpart[(size_t)(pbase + s) * 128 + row * 2 + 1];
      M = fmaxf(M, ms[s]);
    }
    float L = 0.f, acc = 0.f;
#pragma unroll
    for (int s = 0; s < 16; ++s) {
      float e = __expf(ms[s] - M);
      L += ls[s] * e;
      acc += e * Opart[(size_t)(pbase + s) * 4096 + row * 64 + lane];
    }
    int r = qb * 64 + row;
    OUT[((size_t)b * SEQ + r) * HS + (size_t)h * DH + lane] = acc / L;
  }
}

extern "C" void kernel_launch(void* const* d_in, const int* in_sizes, int n_in,
                              void* d_out, int out_size, void* d_ws, size_t ws_size,
                              hipStream_t stream) {
  const float* X  = (const float*)d_in[0];
  const float* Wq = (const float*)d_in[1];
  const float* bq = (const float*)d_in[2];
  const float* Wk = (const float*)d_in[3];
  const float* bk = (const float*)d_in[4];
  const float* Wv = (const float*)d_in[5];
  const float* bv = (const float*)d_in[6];
  float* out = (float*)d_out;

  u16* Xb  = (u16*)d_ws;                 // 16,777,216 elems (33.5 MB)
  u16* Wqb = Xb + 16777216;              // 1,048,576 (2 MB)
  u16* Wkb = Wqb + 1048576;
  u16* Wvb = Wkb + 1048576;
  u16* Qb  = Wvb + 1048576;
  u16* Kb  = Qb + 16777216;
  u16* Vb  = Kb + 16777216;

  // partial buffers alias Xb/Wqb (dead after gemm_qkv)
  float* Opart  = (float*)Xb;            // 2048 * 4096 floats = 33.5 MB
  float* MLpart = (float*)Wqb;           // 2048 * 128 floats = 1 MB

  cvt_kernel<<<2048, 256, 0, stream>>>(X, Xb, 16777216);
  cvt_w_kernel<<<dim3(256, 3), 256, 0, stream>>>(Wq, Wk, Wv, Wqb, Wkb, Wvb, 1048576);
  gemm_qkv<<<dim3(128, 8, 3), 256, 0, stream>>>(Xb, Wqb, Wkb, Wvb, bq, bk, bv, Qb, Kb, Vb);
  bigbird_attn2<<<6016, 256, 0, stream>>>(Qb, Kb, Vb, out, Opart, MLpart);
  bigbird_combine<<<128, 256, 0, stream>>>(Opart, MLpart, out);
}